// Round 1
// baseline (856.763 us; speedup 1.0000x reference)
//
#include <hip/hip_runtime.h>
#include <stdint.h>

// Problem constants (SelfAttention_7481833030271)
//   x:  (64, 8192, 64) f32  == [P=32768 positions][K=1024] (pos = (n,l), K = (c,d))
//   Wq: (8, 16, 64, 32) f32 == [h][k=c*64+d'][t]
//   Wk: (8, 64, 32) f32     == [h][d][t]
//   out:(64, 512, 512) f32  == [pos][h*64+d]
// Folded matrix: M[h][k][d] = sum_t Wq[h][k][t]*Wk[h][d][t] / sqrt(32)
// Then per position: A[h][d] = sum_k x[k] M[h][k][d];  QK[c] = sum_d x[c*64+d]*A[h][d];
// softmax over c (16); out[h][d] = sum_c w_c x[c*64+d].

#define KTOT   1024
#define P_TOT  32768
#define BM     64          // positions per block
#define KSTEPS 32          // K / 32
#define NPASS  2           // head-groups of 4 (256 cols each)

typedef __attribute__((ext_vector_type(4))) float  f32x4;
typedef __attribute__((ext_vector_type(8))) __bf16 bf16x8;
typedef __attribute__((ext_vector_type(4))) unsigned int u32x4;

#define XLDS_BYTES 131072              // 64 rows * 1024 bf16 * 2B (swizzled)
#define WQOFF      131072              // 2 x 16KB M-staging dbuf; reused as A-tile (64x256 bf16)
#define LDS_TOTAL  163840

// Precomputed folded matrix, bf16, MFMA-B-fragment-ready layout:
// idx = ((p*32+s)*16 + ct)*512 + lane*8 + j  <->  B_p[k=32s+(lane>>4)*8+j][col=16ct+(lane&15)]
// with col = (h-4p)*64 + d.
__device__ unsigned short g_Mpre[2 * 32 * 8192];   // 1 MB

__device__ __forceinline__ unsigned short f2bf(float f) {
  unsigned int u = __float_as_uint(f);
  u += 0x7FFFu + ((u >> 16) & 1u);                 // RNE
  return (unsigned short)(u >> 16);
}
__device__ __forceinline__ float bflo(unsigned int w) { return __uint_as_float(w << 16); }
__device__ __forceinline__ float bfhi(unsigned int w) { return __uint_as_float(w & 0xFFFF0000u); }

// ---------------- pre-kernel: fold Wq,Wk -> M (bf16, fragment-ready) ----------------
__global__ void __launch_bounds__(256)
fold_wqk(const float* __restrict__ Wq, const float* __restrict__ Wk) {
  int idx = (blockIdx.x << 8) + threadIdx.x;       // 524288 total
  int j  = idx & 7;
  int l  = (idx >> 3) & 63;
  int ct = (idx >> 9) & 15;
  int s  = (idx >> 13) & 31;
  int pp = idx >> 18;                              // 0..1
  int k   = (s << 5) + ((l >> 4) << 3) + j;        // 0..1023
  int col = (ct << 4) + (l & 15);                  // 0..255
  int h   = (pp << 2) + (col >> 6);
  int d   = col & 63;
  const float* wq = Wq + ((size_t)h << 15) + ((size_t)k << 5);   // [h][k][t]
  const float* wk = Wk + ((size_t)h << 11) + ((size_t)d << 5);   // [h][d][t]
  float acc = 0.f;
#pragma unroll
  for (int t = 0; t < 32; ++t) acc = fmaf(wq[t], wk[t], acc);
  g_Mpre[idx] = f2bf(acc * 0.17677669529663687f); // 1/sqrt(32) folded in
}

// ---------------- main fused kernel ----------------
__global__ void __launch_bounds__(512, 2)
attn_main(const float* __restrict__ x, float* __restrict__ out) {
  extern __shared__ char smem[];
  const int tid  = threadIdx.x;
  const int lane = tid & 63;
  const int wave = tid >> 6;
  const int pos0 = blockIdx.x << 6;
  const float* xblk = x + ((size_t)pos0 << 10);

  const int wm = wave >> 2;          // 0..1  (32-row slab)
  const int wn = wave & 3;           // 0..3  (64-col slab)
  const int xr = tid >> 3;           // x-staging row 0..63
  const int xk = (tid & 7) << 2;     // x-staging k-offset (floats) within 32-chunk

  for (int p = 0; p < NPASS; ++p) {
    f32x4 acc[2][4];
#pragma unroll
    for (int mt = 0; mt < 2; ++mt)
#pragma unroll
      for (int ct = 0; ct < 4; ++ct)
#pragma unroll
        for (int r = 0; r < 4; ++r) acc[mt][ct][r] = 0.0f;

    // ---- prologue: stage M chunk 0 (and x chunk 0 on pass 0)
    {
      const bf16x8* sp = (const bf16x8*)(g_Mpre + ((size_t)(p << 5) << 13)) + (tid << 1);
      bf16x8 w0 = sp[0], w1 = sp[1];
      bf16x8* dp = (bf16x8*)(smem + WQOFF) + (tid << 1);
      dp[0] = w0; dp[1] = w1;
      if (p == 0) {
        float4 xv = *(const float4*)(xblk + (size_t)xr * KTOT + xk);
        unsigned int lo = ((unsigned int)f2bf(xv.y) << 16) | f2bf(xv.x);
        unsigned int hi = ((unsigned int)f2bf(xv.w) << 16) | f2bf(xv.z);
        unsigned int off = ((unsigned int)xr << 11) + ((unsigned int)xk << 1);
        off ^= (unsigned int)(xr & 7) << 4;
        *(uint2*)(smem + off) = make_uint2(lo, hi);
      }
    }
    __syncthreads();

    // ---- K loop: 32 steps of K=32
    for (int s = 0; s < KSTEPS; ++s) {
      bf16x8 w0, w1; float4 xv;
      const bool more = (s + 1) < KSTEPS;
      if (more) {  // issue next-chunk global loads early (hidden under MFMAs)
        const bf16x8* sp = (const bf16x8*)(g_Mpre + ((size_t)(p * 32 + s + 1) << 13)) + (tid << 1);
        w0 = sp[0]; w1 = sp[1];
        if (p == 0) xv = *(const float4*)(xblk + (size_t)xr * KTOT + (s + 1) * 32 + xk);
      }
      {  // MFMA on chunk s
        const char* wb = smem + WQOFF + ((s & 1) << 14);
        bf16x8 a[2], b[4];
#pragma unroll
        for (int mt = 0; mt < 2; ++mt) {
          int row = (wm << 5) + (mt << 4) + (lane & 15);
          unsigned int off = ((unsigned int)row << 11) + ((unsigned int)((s << 5) + ((lane >> 4) << 3)) << 1);
          off ^= (unsigned int)(row & 7) << 4;
          a[mt] = *(const bf16x8*)(smem + off);
        }
#pragma unroll
        for (int ct = 0; ct < 4; ++ct) {
          int ctg = (wn << 2) + ct;
          b[ct] = *(const bf16x8*)(wb + (((ctg << 6) + lane) << 4));
        }
#pragma unroll
        for (int mt = 0; mt < 2; ++mt)
#pragma unroll
          for (int ct = 0; ct < 4; ++ct)
            acc[mt][ct] = __builtin_amdgcn_mfma_f32_16x16x32_bf16(a[mt], b[ct], acc[mt][ct], 0, 0, 0);
      }
      if (more) {  // commit staged data for chunk s+1 (disjoint LDS regions vs reads of s)
        bf16x8* dp = (bf16x8*)(smem + WQOFF + (((s + 1) & 1) << 14)) + (tid << 1);
        dp[0] = w0; dp[1] = w1;
        if (p == 0) {
          unsigned int lo = ((unsigned int)f2bf(xv.y) << 16) | f2bf(xv.x);
          unsigned int hi = ((unsigned int)f2bf(xv.w) << 16) | f2bf(xv.z);
          unsigned int off = ((unsigned int)xr << 11) + ((unsigned int)(((s + 1) << 5) + xk) << 1);
          off ^= (unsigned int)(xr & 7) << 4;
          *(uint2*)(smem + off) = make_uint2(lo, hi);
        }
      }
      __syncthreads();
    }

    // ---- spill A-tile (acc) to LDS as bf16 [64 pos][256 col], pos-swizzled
    {
      char* ab = smem + WQOFF;
#pragma unroll
      for (int mt = 0; mt < 2; ++mt)
#pragma unroll
        for (int ct = 0; ct < 4; ++ct)
#pragma unroll
          for (int r = 0; r < 4; ++r) {
            int pos = (wm << 5) + (mt << 4) + ((lane >> 4) << 2) + r;  // C: row=(lane>>4)*4+r
            int col = (wn << 6) + (ct << 4) + (lane & 15);             // C: col=lane&15
            unsigned int off = ((unsigned int)pos << 9) + ((unsigned int)col << 1);
            off ^= (unsigned int)(pos & 7) << 4;
            *(unsigned short*)(ab + off) = f2bf(acc[mt][ct][r]);
          }
    }
    __syncthreads();

    // ---- epilogue: 512 threads = 64 pos x 4 heads x 2 d-halves
    {
      const char* ab = smem + WQOFF;
      const int half = tid & 1;
      const int pos  = (tid >> 1) & 63;
      const int hp   = tid >> 7;               // 0..3 (head within pass)
      const unsigned int swz = (unsigned int)(pos & 7) << 4;

      // load A[d] for this (pos, head), d in [half*32, half*32+32)
      float av[32];
      {
        unsigned int base = ((unsigned int)pos << 9) + ((unsigned int)((hp << 6) + (half << 5)) << 1);
#pragma unroll
        for (int d0 = 0; d0 < 4; ++d0) {
          u32x4 v = *(const u32x4*)(ab + ((base + (d0 << 4)) ^ swz));
#pragma unroll
          for (int i = 0; i < 4; ++i) {
            av[d0 * 8 + 2 * i]     = bflo(v[i]);
            av[d0 * 8 + 2 * i + 1] = bfhi(v[i]);
          }
        }
      }

      const unsigned int xbase = ((unsigned int)pos << 11) + ((unsigned int)(half << 5) << 1);

      // QK[c] = sum_d x[c,d] * A[d]   (half-split, combined via shfl_xor(1))
      float qk[16];
#pragma unroll
      for (int c = 0; c < 16; ++c) {
        float dot0 = 0.f, dot1 = 0.f;
        unsigned int cb = xbase + ((unsigned int)(c << 6) << 1);
#pragma unroll
        for (int d0 = 0; d0 < 4; ++d0) {
          u32x4 v = *(const u32x4*)(smem + ((cb + (d0 << 4)) ^ swz));
#pragma unroll
          for (int i = 0; i < 4; ++i) {
            dot0 = fmaf(bflo(v[i]), av[d0 * 8 + 2 * i],     dot0);
            dot1 = fmaf(bfhi(v[i]), av[d0 * 8 + 2 * i + 1], dot1);
          }
        }
        float dt = dot0 + dot1;
        qk[c] = dt + __shfl_xor(dt, 1, 64);
      }

      float mx = qk[0];
#pragma unroll
      for (int c = 1; c < 16; ++c) mx = fmaxf(mx, qk[c]);
      float e[16]; float sum = 0.f;
#pragma unroll
      for (int c = 0; c < 16; ++c) { e[c] = __expf(qk[c] - mx); sum += e[c]; }
      float inv = 1.0f / sum;

      float o[32];
#pragma unroll
      for (int j = 0; j < 32; ++j) o[j] = 0.f;
#pragma unroll
      for (int c = 0; c < 16; ++c) {
        float ec = e[c] * inv;
        unsigned int cb = xbase + ((unsigned int)(c << 6) << 1);
#pragma unroll
        for (int d0 = 0; d0 < 4; ++d0) {
          u32x4 v = *(const u32x4*)(smem + ((cb + (d0 << 4)) ^ swz));
#pragma unroll
          for (int i = 0; i < 4; ++i) {
            o[d0 * 8 + 2 * i]     = fmaf(bflo(v[i]), ec, o[d0 * 8 + 2 * i]);
            o[d0 * 8 + 2 * i + 1] = fmaf(bfhi(v[i]), ec, o[d0 * 8 + 2 * i + 1]);
          }
        }
      }

      float* op = out + ((size_t)(pos0 + pos) << 9) + (size_t)(((p << 2) + hp) << 6) + (half << 5);
#pragma unroll
      for (int q = 0; q < 8; ++q)
        *(float4*)(op + (q << 2)) = make_float4(o[q * 4], o[q * 4 + 1], o[q * 4 + 2], o[q * 4 + 3]);
    }
    __syncthreads();   // protect A-tile/M-staging region before next pass
  }
}

extern "C" void kernel_launch(void* const* d_in, const int* in_sizes, int n_in,
                              void* d_out, int out_size, void* d_ws, size_t ws_size,
                              hipStream_t stream) {
  (void)in_sizes; (void)n_in; (void)d_ws; (void)ws_size; (void)out_size;
  const float* x  = (const float*)d_in[0];
  const float* Wq = (const float*)d_in[1];
  const float* Wk = (const float*)d_in[2];
  float* out = (float*)d_out;

  // allow 160 KB dynamic LDS (idempotent; ignore failure — sticky after first call)
  (void)hipFuncSetAttribute((const void*)attn_main,
                            hipFuncAttributeMaxDynamicSharedMemorySize, LDS_TOTAL);

  fold_wqk<<<2048, 256, 0, stream>>>(Wq, Wk);
  attn_main<<<P_TOT / BM, 512, LDS_TOTAL, stream>>>(x, out);
}

// Round 2
// 395.567 us; speedup vs baseline: 2.1659x; 2.1659x over previous
//
#include <hip/hip_runtime.h>
#include <stdint.h>

// SelfAttention: x(64,8192,64)f32 = [P=32768][K=1024], Wq(8,16,64,32), Wk(8,64,32)
// out(64,512,512)f32 = [pos][h*64+d]
// Fold: M[k][col=h*64+d] = sum_t Wq[h][k][t]*Wk[h][d][t]/sqrt(32)   (1024x512)
// K1:   A = bf16(x) . M          (32768x512, bf16 out)
// K2:   QK[c]=sum_d x[c,d]A[h,d]; softmax over c(16); out[h,d]=sum_c w_c x[c,d]

typedef __attribute__((ext_vector_type(4))) float  f32x4;
typedef __attribute__((ext_vector_type(8))) __bf16 bf16x8;
typedef __attribute__((ext_vector_type(4))) unsigned int u32x4;

#define P_TOT 32768
#define NCOL  512

// M, fragment-ready: flat idx = ((skk*32 + ctg)*64 + lane)*8 + j
//  <-> M[k = skk*32 + (lane>>4)*8 + j][col = ctg*16 + (lane&15)]
__device__ __align__(16) unsigned short g_Mpre[524288];          // 1 MB
__device__ __align__(16) unsigned short g_A[(size_t)P_TOT * NCOL]; // 33.5 MB

static __device__ __forceinline__ unsigned short f2bf(float f) {
  unsigned int u = __float_as_uint(f);
  u += 0x7FFFu + ((u >> 16) & 1u);               // RNE
  return (unsigned short)(u >> 16);
}
static __device__ __forceinline__ unsigned int pk2(float lo, float hi) {
  return ((unsigned int)f2bf(hi) << 16) | (unsigned int)f2bf(lo);
}
static __device__ __forceinline__ float bflo(unsigned int w) { return __uint_as_float(w << 16); }
static __device__ __forceinline__ float bfhi(unsigned int w) { return __uint_as_float(w & 0xFFFF0000u); }

// ---------------- fold: Wq,Wk -> M (bf16, fragment-ready) ----------------
__global__ void __launch_bounds__(256)
fold_wqk(const float* __restrict__ Wq, const float* __restrict__ Wk) {
  int idx  = (blockIdx.x << 8) + threadIdx.x;    // 524288
  int j    = idx & 7;
  int lane = (idx >> 3) & 63;
  int ctg  = (idx >> 9) & 31;
  int skk  = idx >> 14;                          // 0..31
  int k    = (skk << 5) + ((lane >> 4) << 3) + j;
  int col  = (ctg << 4) + (lane & 15);
  int h    = col >> 6;
  int d    = col & 63;
  const float* wq = Wq + ((size_t)h << 15) + ((size_t)k << 5);
  const float* wk = Wk + ((size_t)h << 11) + ((size_t)d << 5);
  float acc = 0.f;
#pragma unroll
  for (int t = 0; t < 32; ++t) acc = fmaf(wq[t], wk[t], acc);
  g_Mpre[idx] = f2bf(acc * 0.17677669529663687f);  // 1/sqrt(32)
}

// ---------------- K1: A = bf16(x) . M   (128x128 tile, BK=64) ----------------
__global__ void __launch_bounds__(256, 2)
gemm_A(const float* __restrict__ x) {
  extern __shared__ char smem[];   // [x buf0 16K][x buf1 16K][m buf0 16K][m buf1 16K]
  const int tid  = threadIdx.x;
  const int lane = tid & 63;
  const int wave = tid >> 6;
  const int wm   = wave >> 1;      // row slab 0..1
  const int wn   = wave & 1;       // col slab 0..1

  const int bid = blockIdx.x;                       // 1024 blocks
  const int swz = ((bid & 7) << 7) + (bid >> 3);    // bijective XCD chunk swizzle
  const int bn  = swz & 3;                          // col panel (128 cols)
  const int pm  = swz >> 2;                         // row panel (128 rows)
  const float* xb = x + ((size_t)pm << 17);         // pm*128*1024

  const int srow = tid >> 1;       // staging row 0..127
  const int skh  = tid & 1;        // staging k-half (32 floats)

  f32x4 acc[4][4];
#pragma unroll
  for (int mt = 0; mt < 4; ++mt)
#pragma unroll
    for (int nt = 0; nt < 4; ++nt)
#pragma unroll
      for (int r = 0; r < 4; ++r) acc[mt][nt][r] = 0.f;

  // prologue: stage step 0
  {
    const float* src = xb + (size_t)srow * 1024 + (skh << 5);
#pragma unroll
    for (int q = 0; q < 4; ++q) {
      f32x4 a = ((const f32x4*)src)[q * 2];
      f32x4 b = ((const f32x4*)src)[q * 2 + 1];
      u32x4 w; w[0] = pk2(a[0], a[1]); w[1] = pk2(a[2], a[3]);
               w[2] = pk2(b[0], b[1]); w[3] = pk2(b[2], b[3]);
      unsigned off = ((unsigned)srow << 7) + ((unsigned)skh << 6) + ((unsigned)q << 4);
      off ^= ((unsigned)srow & 7u) << 4;
      *(u32x4*)(smem + off) = w;
    }
#pragma unroll
    for (int i = 0; i < 4; ++i) {
      int g  = tid + (i << 8);                     // 0..1023
      int kk = g >> 9, ct8 = (g >> 6) & 7, lp = g & 63;
      size_t sidx = ((size_t)((kk << 5) + (bn << 3) + ct8) << 9) + ((size_t)lp << 3);
      *(u32x4*)(smem + 32768 + (g << 4)) = *(const u32x4*)(g_Mpre + sidx);
    }
  }
  __syncthreads();

  int buf = 0;
  for (int s = 0; s < 16; ++s) {
    f32x4 xv[8]; u32x4 mv[4];
    const bool more = (s + 1) < 16;
    if (more) {
      const float* src = xb + (size_t)srow * 1024 + ((s + 1) << 6) + (skh << 5);
#pragma unroll
      for (int q = 0; q < 8; ++q) xv[q] = ((const f32x4*)src)[q];
#pragma unroll
      for (int i = 0; i < 4; ++i) {
        int g  = tid + (i << 8);
        int kk = g >> 9, ct8 = (g >> 6) & 7, lp = g & 63;
        size_t sidx = ((size_t)((((s + 1) * 2 + kk) << 5) + (bn << 3) + ct8) << 9) + ((size_t)lp << 3);
        mv[i] = *(const u32x4*)(g_Mpre + sidx);
      }
    }
    // MFMA on buf
    {
      const char* xl = smem + (buf << 14);
      const char* ml = smem + 32768 + (buf << 14);
#pragma unroll
      for (int kk = 0; kk < 2; ++kk) {
        bf16x8 a[4], b[4];
#pragma unroll
        for (int mt = 0; mt < 4; ++mt) {
          int row = (wm << 6) + (mt << 4) + (lane & 15);
          unsigned off = ((unsigned)row << 7) + ((unsigned)kk << 6) + (((unsigned)lane >> 4) << 4);
          off ^= ((unsigned)row & 7u) << 4;
          a[mt] = *(const bf16x8*)(xl + off);
        }
#pragma unroll
        for (int nt = 0; nt < 4; ++nt)
          b[nt] = *(const bf16x8*)(ml + (kk << 13) + (((((wn << 2) + nt) << 6) + lane) << 4));
#pragma unroll
        for (int mt = 0; mt < 4; ++mt)
#pragma unroll
          for (int nt = 0; nt < 4; ++nt)
            acc[mt][nt] = __builtin_amdgcn_mfma_f32_16x16x32_bf16(a[mt], b[nt], acc[mt][nt], 0, 0, 0);
      }
    }
    if (more) {  // commit prefetch into other buffer
      char* xd = smem + ((buf ^ 1) << 14);
#pragma unroll
      for (int q = 0; q < 4; ++q) {
        u32x4 w; w[0] = pk2(xv[q*2][0], xv[q*2][1]); w[1] = pk2(xv[q*2][2], xv[q*2][3]);
                 w[2] = pk2(xv[q*2+1][0], xv[q*2+1][1]); w[3] = pk2(xv[q*2+1][2], xv[q*2+1][3]);
        unsigned off = ((unsigned)srow << 7) + ((unsigned)skh << 6) + ((unsigned)q << 4);
        off ^= ((unsigned)srow & 7u) << 4;
        *(u32x4*)(xd + off) = w;
      }
      char* md = smem + 32768 + ((buf ^ 1) << 14);
#pragma unroll
      for (int i = 0; i < 4; ++i)
        *(u32x4*)(md + ((tid + (i << 8)) << 4)) = mv[i];
    }
    __syncthreads();
    buf ^= 1;
  }

  // C-write (bf16) to g_A
#pragma unroll
  for (int mt = 0; mt < 4; ++mt)
#pragma unroll
    for (int nt = 0; nt < 4; ++nt)
#pragma unroll
      for (int r = 0; r < 4; ++r) {
        size_t row = ((size_t)pm << 7) + (wm << 6) + (mt << 4) + ((lane >> 4) << 2) + r;
        int    col = (bn << 7) + (wn << 6) + (nt << 4) + (lane & 15);
        g_A[(row << 9) + col] = f2bf(acc[mt][nt][r]);
      }
}

// ---------------- K2: epilogue (QK, softmax, weighted sum) ----------------
__global__ void __launch_bounds__(512)
attn_ep(const float* __restrict__ x, float* __restrict__ out) {
  __shared__ char xs[32768];       // 16 pos x 1024 bf16 (swizzled)
  const int tid  = threadIdx.x;
  const int pos0 = blockIdx.x << 4;

  // stage x -> bf16 LDS
  {
    const float* src = x + ((size_t)pos0 << 10);
#pragma unroll
    for (int i = 0; i < 4; ++i) {
      int g = tid + (i << 9);                     // 0..2047 granules of 16B
      f32x4 a = *(const f32x4*)(src + ((size_t)g << 3));
      f32x4 b = *(const f32x4*)(src + ((size_t)g << 3) + 4);
      u32x4 w; w[0] = pk2(a[0], a[1]); w[1] = pk2(a[2], a[3]);
               w[2] = pk2(b[0], b[1]); w[3] = pk2(b[2], b[3]);
      unsigned off = (unsigned)g << 4;
      off ^= (((unsigned)g >> 7) & 1u) << 4;      // pos-parity XOR on d0-bit
      *(u32x4*)(xs + off) = w;
    }
  }
  __syncthreads();

  const int q   = tid & 3;                        // d-quarter
  const int h   = (tid >> 2) & 7;
  const int pos = tid >> 5;                       // 0..15
  const unsigned pswz = ((unsigned)pos & 1u) << 4;

  // A fragment: 16 bf16 -> f32
  float av[16];
  {
    const unsigned short* ap = g_A + (((size_t)(pos0 + pos)) << 9) + (h << 6) + (q << 4);
    u32x4 w0 = *(const u32x4*)ap;
    u32x4 w1 = *(const u32x4*)(ap + 8);
#pragma unroll
    for (int i = 0; i < 4; ++i) {
      av[2*i]     = bflo(w0[i]);  av[2*i + 1] = bfhi(w0[i]);
      av[8 + 2*i] = bflo(w1[i]);  av[9 + 2*i] = bfhi(w1[i]);
    }
  }

  const unsigned xbase = ((unsigned)pos << 11) + ((unsigned)q << 5);

  float qk[16];
#pragma unroll
  for (int c = 0; c < 16; ++c) {
    unsigned cb = xbase + ((unsigned)c << 7);
    u32x4 v0 = *(const u32x4*)(xs + (cb ^ pswz));
    u32x4 v1 = *(const u32x4*)(xs + ((cb + 16u) ^ pswz));
    float dt = 0.f;
#pragma unroll
    for (int i = 0; i < 4; ++i) {
      dt = fmaf(bflo(v0[i]), av[2*i],     dt);
      dt = fmaf(bfhi(v0[i]), av[2*i + 1], dt);
      dt = fmaf(bflo(v1[i]), av[8 + 2*i], dt);
      dt = fmaf(bfhi(v1[i]), av[9 + 2*i], dt);
    }
    dt += __shfl_xor(dt, 1, 64);
    dt += __shfl_xor(dt, 2, 64);
    qk[c] = dt;
  }

  float mx = qk[0];
#pragma unroll
  for (int c = 1; c < 16; ++c) mx = fmaxf(mx, qk[c]);
  float sum = 0.f;
#pragma unroll
  for (int c = 0; c < 16; ++c) { qk[c] = __expf(qk[c] - mx); sum += qk[c]; }
  const float inv = 1.0f / sum;

  float o[16];
#pragma unroll
  for (int i = 0; i < 16; ++i) o[i] = 0.f;
#pragma unroll
  for (int c = 0; c < 16; ++c) {
    float wc = qk[c] * inv;
    unsigned cb = xbase + ((unsigned)c << 7);
    u32x4 v0 = *(const u32x4*)(xs + (cb ^ pswz));
    u32x4 v1 = *(const u32x4*)(xs + ((cb + 16u) ^ pswz));
#pragma unroll
    for (int i = 0; i < 4; ++i) {
      o[2*i]     = fmaf(bflo(v0[i]), wc, o[2*i]);
      o[2*i + 1] = fmaf(bfhi(v0[i]), wc, o[2*i + 1]);
      o[8 + 2*i] = fmaf(bflo(v1[i]), wc, o[8 + 2*i]);
      o[9 + 2*i] = fmaf(bfhi(v1[i]), wc, o[9 + 2*i]);
    }
  }

  float* op = out + (((size_t)(pos0 + pos)) << 9) + (h << 6) + (q << 4);
#pragma unroll
  for (int j = 0; j < 4; ++j)
    *(f32x4*)(op + (j << 2)) = *(f32x4*)&o[j * 4];
}

extern "C" void kernel_launch(void* const* d_in, const int* in_sizes, int n_in,
                              void* d_out, int out_size, void* d_ws, size_t ws_size,
                              hipStream_t stream) {
  (void)in_sizes; (void)n_in; (void)d_ws; (void)ws_size; (void)out_size;
  const float* x  = (const float*)d_in[0];
  const float* Wq = (const float*)d_in[1];
  const float* Wk = (const float*)d_in[2];
  float* out = (float*)d_out;

  (void)hipFuncSetAttribute((const void*)gemm_A,
                            hipFuncAttributeMaxDynamicSharedMemorySize, 65536);

  fold_wqk<<<2048, 256, 0, stream>>>(Wq, Wk);
  gemm_A<<<1024, 256, 65536, stream>>>(x);
  attn_ep<<<P_TOT / 16, 512, 0, stream>>>(x, out);
}

// Round 3
// 369.944 us; speedup vs baseline: 2.3159x; 1.0693x over previous
//
#include <hip/hip_runtime.h>
#include <stdint.h>

// SelfAttention: x(64,8192,64)f32 = [P=32768][K=1024], Wq(8,16,64,32), Wk(8,64,32)
// out(64,512,512)f32 = [pos][h*64+d]
// Pipeline:
//   cvt : g_xbf = bf16(x)                       (201 MB BW pass, warms L3)
//   fold: M[k][col=h*64+d] = Wq.Wk^T/sqrt(32)   (bf16, MFMA-fragment-ready)
//   K1  : g_A = g_xbf . M                        (32768x512 GEMM, global_load_lds staging)
//   K2  : QK[c]=sum_d x[c,d]A[h,d]; softmax(16); out = sum_c w_c x[c,d]

typedef __attribute__((ext_vector_type(4))) float  f32x4;
typedef __attribute__((ext_vector_type(8))) __bf16 bf16x8;
typedef __attribute__((ext_vector_type(4))) unsigned int u32x4;

#define P_TOT 32768

__device__ __align__(16) unsigned short g_Mpre[524288];               // 1 MB
__device__ __align__(16) unsigned short g_A[(size_t)P_TOT * 512];     // 33.5 MB
__device__ __align__(16) unsigned short g_xbf[(size_t)P_TOT * 1024];  // 67 MB

static __device__ __forceinline__ unsigned short f2bf(float f) {
  unsigned int u = __float_as_uint(f);
  u += 0x7FFFu + ((u >> 16) & 1u);               // RNE
  return (unsigned short)(u >> 16);
}
static __device__ __forceinline__ unsigned int pk2(float lo, float hi) {
  return ((unsigned int)f2bf(hi) << 16) | (unsigned int)f2bf(lo);
}
static __device__ __forceinline__ float bflo(unsigned int w) { return __uint_as_float(w << 16); }
static __device__ __forceinline__ float bfhi(unsigned int w) { return __uint_as_float(w & 0xFFFF0000u); }

// global(16B) -> LDS direct copy; dest is wave-uniform base + lane*16 (HW rule).
typedef __attribute__((address_space(3))) void lds_void;
typedef const __attribute__((address_space(1))) void gbl_void;
static __device__ __forceinline__ void glds16(const void* g, void* l) {
  __builtin_amdgcn_global_load_lds((gbl_void*)(uintptr_t)g,
                                   (lds_void*)(uint32_t)(uintptr_t)l, 16, 0, 0);
}

// ---------------- cvt: x f32 -> bf16 ----------------
__global__ void __launch_bounds__(256)
cvt_x(const float* __restrict__ x) {
  int g = (blockIdx.x << 10) + threadIdx.x;      // granule of 8 elems
#pragma unroll
  for (int i = 0; i < 4; ++i, g += 256) {
    const f32x4* src = (const f32x4*)(x + ((size_t)g << 3));
    f32x4 a = src[0], b = src[1];
    u32x4 w; w[0] = pk2(a[0], a[1]); w[1] = pk2(a[2], a[3]);
             w[2] = pk2(b[0], b[1]); w[3] = pk2(b[2], b[3]);
    *(u32x4*)(g_xbf + ((size_t)g << 3)) = w;
  }
}

// ---------------- fold: Wq,Wk -> M (bf16, fragment-ready) ----------------
// flat = ((s*32 + ctg)*64 + lane)*8 + j  <->  M[k=s*32+(lane>>4)*8+j][col=ctg*16+(lane&15)]
__global__ void __launch_bounds__(256)
fold_wqk(const float* __restrict__ Wq, const float* __restrict__ Wk) {
  int idx  = (blockIdx.x << 8) + threadIdx.x;    // 524288
  int j    = idx & 7;
  int lane = (idx >> 3) & 63;
  int ctg  = (idx >> 9) & 31;
  int skk  = idx >> 14;                          // 0..31
  int k    = (skk << 5) + ((lane >> 4) << 3) + j;
  int col  = (ctg << 4) + (lane & 15);
  int h    = col >> 6;
  int d    = col & 63;
  const float* wq = Wq + ((size_t)h << 15) + ((size_t)k << 5);
  const float* wk = Wk + ((size_t)h << 11) + ((size_t)d << 5);
  float acc = 0.f;
#pragma unroll
  for (int t = 0; t < 32; ++t) acc = fmaf(wq[t], wk[t], acc);
  g_Mpre[idx] = f2bf(acc * 0.17677669529663687f);  // 1/sqrt(32)
}

// ---------------- K1: A = xbf . M   (128x128 tile, BK=32, all global_load_lds) ----------------
__global__ void __launch_bounds__(256)
gemm_A() {
  __shared__ __align__(16) char xs[2][8192];     // 128 rows x 32 k bf16 (slot-XOR image)
  __shared__ __align__(16) char ms[2][8192];     // 32 k x 128 col bf16 (fragment-ready)
  const int tid  = threadIdx.x;
  const int lane = tid & 63;
  const int wave = tid >> 6;
  const int wm   = wave >> 1;
  const int wn   = wave & 1;

  const int bid = blockIdx.x;                    // 1024 blocks
  const int swz = ((bid & 7) << 7) + (bid >> 3); // bijective XCD chunk swizzle (1024%8==0)
  const int bn  = swz & 3;                       // col panel (128)
  const int pm  = swz >> 2;                      // row panel (128)

  // x staging: dest granule d = i*256 + tid -> row=d>>2, c=d&3; src slot = c ^ ((row>>1)&3)
  const int d0 = tid, d1 = 256 + tid;
  const int xr0 = d0 >> 2, xc0 = (d0 & 3) ^ ((d0 >> 3) & 3);
  const int xr1 = d1 >> 2, xc1 = (d1 & 3) ^ ((d1 >> 3) & 3);
  const char* xg0 = (const char*)g_xbf + (((size_t)(pm * 128 + xr0)) << 11) + (xc0 << 4);
  const char* xg1 = (const char*)g_xbf + (((size_t)(pm * 128 + xr1)) << 11) + (xc1 << 4);
  const char* mg  = (const char*)g_Mpre + ((size_t)bn << 13) + (tid << 4);

  char* xd0 = &xs[0][0] + (wave << 10);
  char* xd1 = &xs[0][0] + 4096 + (wave << 10);
  char* md0 = &ms[0][0] + (wave << 10);
  char* md1 = &ms[0][0] + 4096 + (wave << 10);

  // fragment read offsets
  const int l4    = lane & 15;
  const int aslot = ((lane >> 4) ^ ((lane >> 1) & 3)) << 4;  // matches staging XOR
  const int abase = (((wm << 6) + l4) << 6);                 // + mt*1024 + aslot
  const int bbase = (((wn << 8) + lane) << 4);               // + nt*1024  (wn*4 ctgs)

  f32x4 acc[4][4];
#pragma unroll
  for (int mt = 0; mt < 4; ++mt)
#pragma unroll
    for (int nt = 0; nt < 4; ++nt)
#pragma unroll
      for (int r = 0; r < 4; ++r) acc[mt][nt][r] = 0.f;

#define STAGE(buf, s) do {                                        \
    size_t xo = (size_t)(s) << 6;                                 \
    glds16(xg0 + xo, xd0 + ((buf) << 13));                        \
    glds16(xg1 + xo, xd1 + ((buf) << 13));                        \
    const char* mc = mg + ((size_t)(s) << 15);                    \
    glds16(mc,        md0 + ((buf) << 13));                       \
    glds16(mc + 4096, md1 + ((buf) << 13));                       \
  } while (0)

  STAGE(0, 0);
  __syncthreads();

#pragma unroll 2
  for (int s = 0; s < 32; ++s) {
    const int cb = s & 1;
    if (s + 1 < 32) STAGE(cb ^ 1, s + 1);
    const char* xb = &xs[cb][0];
    const char* mb = &ms[cb][0];
    bf16x8 a[4], b[4];
#pragma unroll
    for (int mt = 0; mt < 4; ++mt)
      a[mt] = *(const bf16x8*)(xb + abase + (mt << 10) + aslot);
#pragma unroll
    for (int nt = 0; nt < 4; ++nt)
      b[nt] = *(const bf16x8*)(mb + bbase + (nt << 10));
#pragma unroll
    for (int mt = 0; mt < 4; ++mt)
#pragma unroll
      for (int nt = 0; nt < 4; ++nt)
        acc[mt][nt] = __builtin_amdgcn_mfma_f32_16x16x32_bf16(a[mt], b[nt], acc[mt][nt], 0, 0, 0);
    __syncthreads();
  }
#undef STAGE

  // C-write (bf16) to g_A
#pragma unroll
  for (int mt = 0; mt < 4; ++mt)
#pragma unroll
    for (int nt = 0; nt < 4; ++nt)
#pragma unroll
      for (int r = 0; r < 4; ++r) {
        size_t row = ((size_t)pm << 7) + (wm << 6) + (mt << 4) + ((lane >> 4) << 2) + r;
        int    col = (bn << 7) + (wn << 6) + (nt << 4) + (lane & 15);
        g_A[(row << 9) + col] = f2bf(acc[mt][nt][r]);
      }
}

// ---------------- K2: epilogue (QK, softmax, weighted sum) ----------------
__global__ void __launch_bounds__(512)
attn_ep(float* __restrict__ out) {
  __shared__ __align__(16) char xsl[32768];      // 16 pos x 1024 bf16, linear
  const int tid  = threadIdx.x;
  const int wave = tid >> 6;
  const int pos0 = blockIdx.x << 4;

  // stage x tile (pure linear copy)
  const char* xg = (const char*)g_xbf + ((size_t)pos0 << 11) + (tid << 4);
#pragma unroll
  for (int i = 0; i < 4; ++i)
    glds16(xg + (i << 13), &xsl[0] + (i << 13) + (wave << 10));

  const int q   = tid & 3;                       // d-quarter
  const int h   = (tid >> 2) & 7;
  const int pos = tid >> 5;                      // 0..15

  // A fragment load issued before the barrier (latency hidden under drain)
  const unsigned short* ap = g_A + (((size_t)(pos0 + pos)) << 9) + (h << 6) + (q << 4);
  u32x4 w0 = *(const u32x4*)ap;
  u32x4 w1 = *(const u32x4*)(ap + 8);
  __syncthreads();

  float av[16];
#pragma unroll
  for (int i = 0; i < 4; ++i) {
    av[2*i]     = bflo(w0[i]);  av[2*i + 1] = bfhi(w0[i]);
    av[8 + 2*i] = bflo(w1[i]);  av[9 + 2*i] = bfhi(w1[i]);
  }

  const char* xb = &xsl[0] + ((unsigned)pos << 11) + ((unsigned)q << 5);

  float qk[16];
#pragma unroll
  for (int c = 0; c < 16; ++c) {
    u32x4 v0 = *(const u32x4*)(xb + (c << 7));
    u32x4 v1 = *(const u32x4*)(xb + (c << 7) + 16);
    float dt = 0.f;
#pragma unroll
    for (int i = 0; i < 4; ++i) {
      dt = fmaf(bflo(v0[i]), av[2*i],     dt);
      dt = fmaf(bfhi(v0[i]), av[2*i + 1], dt);
      dt = fmaf(bflo(v1[i]), av[8 + 2*i], dt);
      dt = fmaf(bfhi(v1[i]), av[9 + 2*i], dt);
    }
    dt += __shfl_xor(dt, 1, 64);
    dt += __shfl_xor(dt, 2, 64);
    qk[c] = dt;
  }

  float mx = qk[0];
#pragma unroll
  for (int c = 1; c < 16; ++c) mx = fmaxf(mx, qk[c]);
  float sum = 0.f;
#pragma unroll
  for (int c = 0; c < 16; ++c) { qk[c] = __expf(qk[c] - mx); sum += qk[c]; }
  const float inv = 1.0f / sum;

  float o[16];
#pragma unroll
  for (int i = 0; i < 16; ++i) o[i] = 0.f;
#pragma unroll
  for (int c = 0; c < 16; ++c) {
    float wc = qk[c] * inv;
    u32x4 v0 = *(const u32x4*)(xb + (c << 7));
    u32x4 v1 = *(const u32x4*)(xb + (c << 7) + 16);
#pragma unroll
    for (int i = 0; i < 4; ++i) {
      o[2*i]     = fmaf(bflo(v0[i]), wc, o[2*i]);
      o[2*i + 1] = fmaf(bfhi(v0[i]), wc, o[2*i + 1]);
      o[8 + 2*i] = fmaf(bflo(v1[i]), wc, o[8 + 2*i]);
      o[9 + 2*i] = fmaf(bfhi(v1[i]), wc, o[9 + 2*i]);
    }
  }

  float* op = out + (((size_t)(pos0 + pos)) << 9) + (h << 6) + (q << 4);
#pragma unroll
  for (int j = 0; j < 4; ++j)
    *(f32x4*)(op + (j << 2)) = *(f32x4*)&o[j * 4];
}

extern "C" void kernel_launch(void* const* d_in, const int* in_sizes, int n_in,
                              void* d_out, int out_size, void* d_ws, size_t ws_size,
                              hipStream_t stream) {
  (void)in_sizes; (void)n_in; (void)d_ws; (void)ws_size; (void)out_size;
  const float* x  = (const float*)d_in[0];
  const float* Wq = (const float*)d_in[1];
  const float* Wk = (const float*)d_in[2];
  float* out = (float*)d_out;

  cvt_x   <<<4096, 256, 0, stream>>>(x);
  fold_wqk<<<2048, 256, 0, stream>>>(Wq, Wk);
  gemm_A  <<<1024, 256, 0, stream>>>();
  attn_ep <<<P_TOT / 16, 512, 0, stream>>>(out);
}